// Round 2
// baseline (248.809 us; speedup 1.0000x reference)
//
#include <hip/hip_runtime.h>
#include <stdint.h>

#define Bz 32
#define Nz 4096
#define Lz 512
#define Dz 256
#define Mz (Bz*Nz)   // 131072 rows

typedef __attribute__((ext_vector_type(8))) short bf16x8;
typedef __attribute__((ext_vector_type(4))) float f32x4;

__device__ __forceinline__ uint32_t f2bf(float f) {
    union { float f; uint32_t u; } v; v.f = f;
    uint32_t u = v.u;
    u += 0x7FFFu + ((u >> 16) & 1u);   // RNE
    return u >> 16;
}

// pack two fp32 -> two bf16 in one op (RNE via MODE default)
__device__ __forceinline__ uint32_t pk2(float a, float b) {
    uint32_t r;
    asm("v_cvt_pk_bf16_f32 %0, %1, %2" : "=v"(r) : "v"(a), "v"(b));
    return r;
}

__device__ __forceinline__ float rcp_(float x) { return __builtin_amdgcn_rcpf(x); }
__device__ __forceinline__ float bf2f(uint32_t u) {
    union { uint32_t u; float f; } v; v.u = u << 16; return v.f;
}

// ---------------------------------------------------------------------------
// Kernel 0: pack [Wa | Wb] into bf16 MFMA-B-fragment order (same as round 1).
// ---------------------------------------------------------------------------
__global__ void pack_w(const float* __restrict__ Wa, const float* __restrict__ Wb,
                       unsigned short* __restrict__ packed)
{
    int tid = blockIdx.x * blockDim.x + threadIdx.x;   // 0..32767
    int ct   = tid >> 10;
    int kt   = (tid >> 6) & 15;
    int lane = tid & 63;
    int k0  = kt * 32 + ((lane >> 4) << 3);
    int col = ct * 16 + (lane & 15);
    const float* W = (col < 256) ? Wa : Wb;
    int c = col & 255;
    bf16x8 v;
    #pragma unroll
    for (int j = 0; j < 8; ++j) v[j] = (short)f2bf(W[(k0 + j) * 256 + c]);
    *(bf16x8*)(&packed[(size_t)tid * 8]) = v;
}

// ---------------------------------------------------------------------------
// Kernel 1: fused GEMM + gated scores + xcopy write-through + pooled partials.
// BM=64 rows/block, 512 threads (8 waves). K split in halves for async stage.
// Outputs per block wg: escore[64] (=exp(s - m_blk)), ms[wg], esums[wg],
// vs[wg][512] (= sum_n exp(s_n - m_blk) * x[n][:], bf16-sourced).
// ---------------------------------------------------------------------------
__global__ __launch_bounds__(512, 4) void fused_scores(
    const float* __restrict__ x, const unsigned short* __restrict__ packedW,
    const float* __restrict__ ba, const float* __restrict__ bb,
    const float* __restrict__ Wc, const float* __restrict__ bc,
    float* __restrict__ xcopy, float* __restrict__ escore,
    float* __restrict__ ms, float* __restrict__ esums,
    float* __restrict__ vs)
{
    __shared__ unsigned short xlds[64 * Lz];   // 64 KiB, XOR-swizzled bf16
    __shared__ float spart[8][64];
    __shared__ float esh[64];
    __shared__ float plds[4][512];

    const int wg   = blockIdx.x;       // 0..2047
    const int row0 = wg * 64;
    const int t    = threadIdx.x;
    const int wave = t >> 6;
    const int lane = t & 63;
    const int lrow = lane & 15;
    const int lkb  = (lane >> 4) << 3;

    const float4* xsrc = (const float4*)(x     + (size_t)row0 * Lz);
    float4*       xdst = (float4*)      (xcopy + (size_t)row0 * Lz);

    // ---- P0: stage K-half 0 (cols 0..255) ----
    #pragma unroll
    for (int i = 0; i < 8; ++i) {
        int lin = i * 512 + t;           // 0..4095 : r = lin>>6, c4 = lin&63
        int r = lin >> 6, c4 = lin & 63;
        float4 v = xsrc[(size_t)r * 128 + c4];
        xdst[(size_t)r * 128 + c4] = v;
        uint32_t off = (uint32_t)(r * 1024 + c4 * 8);
        off ^= (uint32_t)((r & 7) << 4);
        *(uint2*)((char*)xlds + off) = make_uint2(pk2(v.x, v.y), pk2(v.z, v.w));
    }
    __syncthreads();

    f32x4 acc[4][4];
    #pragma unroll
    for (int a = 0; a < 4; ++a)
        #pragma unroll
        for (int b = 0; b < 4; ++b)
            acc[a][b] = (f32x4){0.f, 0.f, 0.f, 0.f};

    const bf16x8* bp0 = (const bf16x8*)packedW;
    const bf16x8* bp[4];
    bp[0] = bp0 + (size_t)((2 * wave)      * 16) * 64 + lane;
    bp[1] = bp0 + (size_t)((2 * wave + 1)  * 16) * 64 + lane;
    bp[2] = bp0 + (size_t)((16 + 2 * wave) * 16) * 64 + lane;
    bp[3] = bp0 + (size_t)((17 + 2 * wave) * 16) * 64 + lane;

    auto KT = [&](int kt) {
        bf16x8 av[4];
        #pragma unroll
        for (int rf = 0; rf < 4; ++rf) {
            int r = rf * 16 + lrow;
            uint32_t off = (uint32_t)(r * 1024 + (kt * 32 + lkb) * 2);
            off ^= (uint32_t)((r & 7) << 4);
            av[rf] = *(const bf16x8*)((const char*)xlds + off);
        }
        #pragma unroll
        for (int cf = 0; cf < 4; ++cf) {
            bf16x8 bv = bp[cf][kt * 64];
            #pragma unroll
            for (int rf = 0; rf < 4; ++rf)
                acc[rf][cf] = __builtin_amdgcn_mfma_f32_16x16x32_bf16(
                                  av[rf], bv, acc[rf][cf], 0, 0, 0);
        }
    };

    // ---- P1: async-stage half 1 (cols 256..511) under MFMA cover ----
    float4 g[4];
    #pragma unroll
    for (int i = 0; i < 4; ++i) {                  // rows 0..31 of half 1
        int lin = i * 512 + t;
        g[i] = xsrc[(size_t)(lin >> 6) * 128 + 64 + (lin & 63)];
    }
    KT(0); KT(1); KT(2); KT(3);
    #pragma unroll
    for (int i = 0; i < 4; ++i) {
        int lin = i * 512 + t;
        int r = lin >> 6, c4 = lin & 63;
        xdst[(size_t)r * 128 + 64 + c4] = g[i];
        uint32_t off = (uint32_t)(r * 1024 + 512 + c4 * 8);
        off ^= (uint32_t)((r & 7) << 4);
        *(uint2*)((char*)xlds + off) = make_uint2(pk2(g[i].x, g[i].y), pk2(g[i].z, g[i].w));
    }
    #pragma unroll
    for (int i = 0; i < 4; ++i) {                  // rows 32..63 of half 1
        int lin = (i + 4) * 512 + t;
        g[i] = xsrc[(size_t)(lin >> 6) * 128 + 64 + (lin & 63)];
    }
    KT(4); KT(5); KT(6); KT(7);
    #pragma unroll
    for (int i = 0; i < 4; ++i) {
        int lin = (i + 4) * 512 + t;
        int r = lin >> 6, c4 = lin & 63;
        xdst[(size_t)r * 128 + 64 + c4] = g[i];
        uint32_t off = (uint32_t)(r * 1024 + 512 + c4 * 8);
        off ^= (uint32_t)((r & 7) << 4);
        *(uint2*)((char*)xlds + off) = make_uint2(pk2(g[i].x, g[i].y), pk2(g[i].z, g[i].w));
    }
    __syncthreads();
    KT(8); KT(9); KT(10); KT(11); KT(12); KT(13); KT(14); KT(15);

    // ---- epilogue: bias + tanh*sigmoid (rcp-based), dot Wc, row reduce ----
    const int d0 = wave * 32 + lrow;
    const int d1 = d0 + 16;
    const float ba0 = ba[d0], ba1 = ba[d1];
    const float bb0 = bb[d0], bb1 = bb[d1];
    const float wc0 = Wc[d0], wc1 = Wc[d1];

    #pragma unroll
    for (int rf = 0; rf < 4; ++rf) {
        #pragma unroll
        for (int r = 0; r < 4; ++r) {
            float pa0 = acc[rf][0][r] + ba0;
            float pa1 = acc[rf][1][r] + ba1;
            float pg0 = acc[rf][2][r] + bb0;
            float pg1 = acc[rf][3][r] + bb1;
            float ea0 = __expf(-2.f * pa0);
            float ea1 = __expf(-2.f * pa1);
            float a0 = 1.f - 2.f * ea0 * rcp_(1.f + ea0);   // tanh
            float a1 = 1.f - 2.f * ea1 * rcp_(1.f + ea1);
            float g0 = rcp_(1.f + __expf(-pg0));            // sigmoid
            float g1 = rcp_(1.f + __expf(-pg1));
            float p = a0 * g0 * wc0 + a1 * g1 * wc1;
            p += __shfl_xor(p, 1);
            p += __shfl_xor(p, 2);
            p += __shfl_xor(p, 4);
            p += __shfl_xor(p, 8);
            if (lrow == 0)
                spart[wave][rf * 16 + ((lane >> 4) << 2) + r] = p;
        }
    }
    __syncthreads();

    // ---- block softmax stats (wave 0 only) ----
    if (t < 64) {
        float s = bc[0];
        #pragma unroll
        for (int w = 0; w < 8; ++w) s += spart[w][t];
        float m = s;
        #pragma unroll
        for (int o = 32; o; o >>= 1) m = fmaxf(m, __shfl_xor(m, o));
        float e = __expf(s - m);
        float es = e;
        #pragma unroll
        for (int o = 32; o; o >>= 1) es += __shfl_xor(es, o);
        esh[t] = e;
        escore[row0 + t] = e;
        if (t == 0) { ms[wg] = m; esums[wg] = es; }
    }
    __syncthreads();

    // ---- pooled partial: v[l] = sum_r e_r * x_bf16[r][l] ----
    {
        const int rg = t >> 7;          // 0..3 : rows rg*16..rg*16+15
        const int cq = t & 127;         // col quad
        const int c0 = cq * 4;
        float a0 = 0.f, a1 = 0.f, a2 = 0.f, a3 = 0.f;
        #pragma unroll
        for (int i = 0; i < 16; ++i) {
            int r = rg * 16 + i;
            float e = esh[r];
            uint32_t off = (uint32_t)(r * 1024 + c0 * 2);
            off ^= (uint32_t)((r & 7) << 4);
            uint2 w = *(const uint2*)((const char*)xlds + off);
            a0 += e * bf2f(w.x & 0xffffu);
            a1 += e * bf2f(w.x >> 16);
            a2 += e * bf2f(w.y & 0xffffu);
            a3 += e * bf2f(w.y >> 16);
        }
        *(float4*)&plds[rg][c0] = make_float4(a0, a1, a2, a3);
    }
    __syncthreads();
    {
        float v = plds[0][t] + plds[1][t] + plds[2][t] + plds[3][t];
        vs[(size_t)wg * 512 + t] = v;
    }
}

// ---------------------------------------------------------------------------
// Kernel 2: per-bag combine. 32 blocks x 512 threads.
// A[b,n] = escore[b,n] * exp(m_c - M_b) / T_b ;  pooled = sum_c alpha_c v_c.
// ---------------------------------------------------------------------------
__global__ __launch_bounds__(512) void combine(
    const float* __restrict__ ms, const float* __restrict__ esums,
    const float* __restrict__ vs, const float* __restrict__ escore,
    float* __restrict__ A, float* __restrict__ pooled)
{
    const int bag = blockIdx.x;
    const int t   = threadIdx.x;
    __shared__ float alpha[64];

    if (t < 64) {
        float m = ms[bag * 64 + t];
        float M = m;
        #pragma unroll
        for (int o = 32; o; o >>= 1) M = fmaxf(M, __shfl_xor(M, o));
        float w = esums[bag * 64 + t] * __expf(m - M);
        float T = w;
        #pragma unroll
        for (int o = 32; o; o >>= 1) T += __shfl_xor(T, o);
        alpha[t] = __expf(m - M) / T;   // precise div, cold path
    }
    __syncthreads();

    float acc = 0.f;
    #pragma unroll 8
    for (int c = 0; c < 64; ++c)
        acc += alpha[c] * vs[((size_t)bag * 64 + c) * 512 + t];
    pooled[(size_t)bag * 512 + t] = acc;

    #pragma unroll
    for (int i = 0; i < 8; ++i) {
        int n = i * 512 + t;
        A[(size_t)bag * Nz + n] = escore[(size_t)bag * Nz + n] * alpha[n >> 6];
    }
}

// ---------------------------------------------------------------------------
extern "C" void kernel_launch(void* const* d_in, const int* in_sizes, int n_in,
                              void* d_out, int out_size, void* d_ws, size_t ws_size,
                              hipStream_t stream)
{
    const float* x  = (const float*)d_in[0];
    const float* Wa = (const float*)d_in[1];
    const float* ba = (const float*)d_in[2];
    const float* Wb = (const float*)d_in[3];
    const float* bb = (const float*)d_in[4];
    const float* Wc = (const float*)d_in[5];
    const float* bc = (const float*)d_in[6];

    float* out    = (float*)d_out;
    float* A      = out;                           // B*N   = 131072
    float* xcopy  = out + (size_t)Mz;              // B*N*L
    float* pooled = xcopy + (size_t)Mz * Lz;       // B*L

    char* ws = (char*)d_ws;
    unsigned short* packed = (unsigned short*)ws;                 // 512 KiB
    float* escore = (float*)(ws + 524288);                        // 512 KiB
    float* ms     = (float*)(ws + 1048576);                       // 8 KiB
    float* esums  = (float*)(ws + 1056768);                       // 8 KiB
    float* vs     = (float*)(ws + 1064960);                       // 4 MiB

    pack_w      <<<128, 256, 0, stream>>>(Wa, Wb, packed);
    fused_scores<<<Mz / 64, 512, 0, stream>>>(x, packed, ba, bb, Wc, bc,
                                              xcopy, escore, ms, esums, vs);
    combine     <<<Bz, 512, 0, stream>>>(ms, esums, vs, escore, A, pooled);
}

// Round 4
// 185.298 us; speedup vs baseline: 1.3427x; 1.3427x over previous
//
#include <hip/hip_runtime.h>
#include <stdint.h>

#define Bz 32
#define Nz 4096
#define Lz 512
#define Dz 256
#define Mz (Bz*Nz)   // 131072 rows

typedef __attribute__((ext_vector_type(8))) short bf16x8;
typedef __attribute__((ext_vector_type(4))) float f32x4;
typedef __attribute__((ext_vector_type(4))) float nf4;   // native vec for NT ops

__device__ __forceinline__ uint32_t f2bf(float f) {
    union { float f; uint32_t u; } v; v.f = f;
    uint32_t u = v.u;
    u += 0x7FFFu + ((u >> 16) & 1u);   // RNE
    return u >> 16;
}

__device__ __forceinline__ uint32_t pk2(float a, float b) {
    uint32_t r;
    asm("v_cvt_pk_bf16_f32 %0, %1, %2" : "=v"(r) : "v"(a), "v"(b));
    return r;
}

__device__ __forceinline__ float rcp_(float x) { return __builtin_amdgcn_rcpf(x); }
__device__ __forceinline__ float bf2f(uint32_t u) {
    union { uint32_t u; float f; } v; v.u = u << 16; return v.f;
}

// ---------------------------------------------------------------------------
// Kernel 0: pack [Wa | Wb] into bf16 B-fragments, laid out so that the GEMM
// reads per (kt, wave) are CONTIGUOUS: packed[((kt*8 + wave)*4 + cf)*64 + lane]
// cf 0/1 = a-coltiles 2w/2w+1, cf 2/3 = g-coltiles 16+2w/17+2w.
// lane l holds W[k = kt*32 + (l>>4)*8 + j][col = ctile*16 + (l&15)], j=0..7.
// ---------------------------------------------------------------------------
__global__ void pack_w(const float* __restrict__ Wa, const float* __restrict__ Wb,
                       unsigned short* __restrict__ packed)
{
    int tid  = blockIdx.x * blockDim.x + threadIdx.x;   // 0..32767
    int lane = tid & 63;
    int cf   = (tid >> 6) & 3;
    int wv   = (tid >> 8) & 7;
    int kt   = tid >> 11;                               // 0..15
    int ctile = (cf < 2) ? (2 * wv + cf) : (16 + 2 * wv + (cf - 2));
    int k0  = kt * 32 + ((lane >> 4) << 3);
    int col = ctile * 16 + (lane & 15);
    const float* W = (col < 256) ? Wa : Wb;
    int c = col & 255;
    bf16x8 v;
    #pragma unroll
    for (int j = 0; j < 8; ++j) v[j] = (short)f2bf(W[(k0 + j) * 256 + c]);
    *(bf16x8*)(&packed[(size_t)tid * 8]) = v;           // index == tid by layout
}

// ---------------------------------------------------------------------------
// Kernel 1: fused GEMM + gated scores + NT xcopy write-through + pooled
// partials. BM=64 rows, 512 threads (8 waves), full K=512 staged at once
// (full-row contiguous IO — the round-2 column split caused cache RMW).
// ---------------------------------------------------------------------------
__global__ __launch_bounds__(512, 4) void fused_scores(
    const float* __restrict__ x, const unsigned short* __restrict__ packedW,
    const float* __restrict__ ba, const float* __restrict__ bb,
    const float* __restrict__ Wc, const float* __restrict__ bc,
    float* __restrict__ xcopy, float* __restrict__ escore,
    float* __restrict__ ms, float* __restrict__ esums,
    float* __restrict__ vs)
{
    __shared__ unsigned short xlds[64 * Lz];   // 64 KiB, XOR-swizzled bf16
    __shared__ float spart[8][64];
    __shared__ float esh[64];
    __shared__ float plds[4][512];

    const int wg   = blockIdx.x;       // 0..2047
    const int row0 = wg * 64;
    const int t    = threadIdx.x;
    const int wave = t >> 6;
    const int lane = t & 63;
    const int lrow = lane & 15;

    // ---- prefetch kt=0 B fragments (independent of LDS, pre-barrier) ----
    const bf16x8* bpk0 = (const bf16x8*)packedW + (size_t)wave * 4 * 64 + lane;
    bf16x8 bv0[4];
    #pragma unroll
    for (int cf = 0; cf < 4; ++cf) bv0[cf] = bpk0[cf * 64];

    // ---- stage: full-row contiguous loads, NT xcopy stores, b128 LDS ----
    const nf4* xsrc = (const nf4*)(x     + (size_t)row0 * Lz);
    nf4*       xdst = (nf4*)      (xcopy + (size_t)row0 * Lz);
    #pragma unroll
    for (int i = 0; i < 8; ++i) {
        int lin = i * 512 + t;                 // 0..4095 ; 64 per row
        nf4 f0 = xsrc[2 * lin];
        nf4 f1 = xsrc[2 * lin + 1];
        __builtin_nontemporal_store(f0, &xdst[2 * lin]);
        __builtin_nontemporal_store(f1, &xdst[2 * lin + 1]);
        int r = lin >> 6, c = lin & 63;
        uint32_t off = (uint32_t)(r * 1024 + c * 16) ^ (uint32_t)((r & 7) << 4);
        uint4 w;
        w.x = pk2(f0.x, f0.y); w.y = pk2(f0.z, f0.w);
        w.z = pk2(f1.x, f1.y); w.w = pk2(f1.z, f1.w);
        *(uint4*)((char*)xlds + off) = w;      // ds_write_b128
    }
    __syncthreads();

    // ---- K loop: all ds_read/global_load via immediate offsets ----
    f32x4 acc[4][4];
    #pragma unroll
    for (int a = 0; a < 4; ++a)
        #pragma unroll
        for (int b = 0; b < 4; ++b)
            acc[a][b] = (f32x4){0.f, 0.f, 0.f, 0.f};

    // swizzle fold: off(rf,kt) = (base ^ s45) +/- s6 + kt*64  (+ for even kt)
    const uint32_t s45 = (uint32_t)((lrow & 3) << 4);
    const uint32_t s6  = (uint32_t)((lrow & 4) << 4);
    const char* xb = (const char*)xlds;
    uint32_t bE[4], bO[4];
    #pragma unroll
    for (int rf = 0; rf < 4; ++rf) {
        uint32_t base = (uint32_t)((rf * 16 + lrow) * 1024 + ((lane >> 4) << 4));
        base ^= s45;
        bE[rf] = base + s6;
        bO[rf] = base - s6;
    }

    #pragma unroll
    for (int kt = 0; kt < 16; ++kt) {
        bf16x8 av[4];
        #pragma unroll
        for (int rf = 0; rf < 4; ++rf)
            av[rf] = *(const bf16x8*)(xb + ((kt & 1) ? bO[rf] : bE[rf]) + kt * 64);
        const bf16x8* bp = (const bf16x8*)packedW
                         + ((size_t)(kt * 8 + wave) * 4) * 64 + lane;
        #pragma unroll
        for (int cf = 0; cf < 4; ++cf) {
            bf16x8 bv = (kt == 0) ? bv0[cf] : bp[cf * 64];
            #pragma unroll
            for (int rf = 0; rf < 4; ++rf)
                acc[rf][cf] = __builtin_amdgcn_mfma_f32_16x16x32_bf16(
                                  av[rf], bv, acc[rf][cf], 0, 0, 0);
        }
    }

    // ---- epilogue: bias + tanh*sigmoid (rcp), dot Wc, per-row reduce ----
    const int d0 = wave * 32 + lrow;
    const int d1 = d0 + 16;
    const float ba0 = ba[d0], ba1 = ba[d1];
    const float bb0 = bb[d0], bb1 = bb[d1];
    const float wc0 = Wc[d0], wc1 = Wc[d1];

    #pragma unroll
    for (int rf = 0; rf < 4; ++rf) {
        #pragma unroll
        for (int r = 0; r < 4; ++r) {
            float pa0 = acc[rf][0][r] + ba0;
            float pa1 = acc[rf][1][r] + ba1;
            float pg0 = acc[rf][2][r] + bb0;
            float pg1 = acc[rf][3][r] + bb1;
            float ea0 = __expf(-2.f * pa0);
            float ea1 = __expf(-2.f * pa1);
            float a0 = 1.f - 2.f * ea0 * rcp_(1.f + ea0);   // tanh
            float a1 = 1.f - 2.f * ea1 * rcp_(1.f + ea1);
            float g0 = rcp_(1.f + __expf(-pg0));            // sigmoid
            float g1 = rcp_(1.f + __expf(-pg1));
            float p = a0 * g0 * wc0 + a1 * g1 * wc1;
            p += __shfl_xor(p, 1);
            p += __shfl_xor(p, 2);
            p += __shfl_xor(p, 4);
            p += __shfl_xor(p, 8);
            if (lrow == 0)
                spart[wave][rf * 16 + ((lane >> 4) << 2) + r] = p;
        }
    }
    __syncthreads();

    // ---- block softmax stats (wave 0) ----
    if (t < 64) {
        float s = bc[0];
        #pragma unroll
        for (int w = 0; w < 8; ++w) s += spart[w][t];
        float m = s;
        #pragma unroll
        for (int o = 32; o; o >>= 1) m = fmaxf(m, __shfl_xor(m, o));
        float e = __expf(s - m);
        float es = e;
        #pragma unroll
        for (int o = 32; o; o >>= 1) es += __shfl_xor(es, o);
        esh[t] = e;
        escore[row0 + t] = e;
        if (t == 0) { ms[wg] = m; esums[wg] = es; }
    }
    __syncthreads();

    // ---- pooled partial: v[l] = sum_r e_r * x_bf16[r][l] ----
    {
        const int rg = t >> 7;          // 0..3 : rows rg*16..rg*16+15
        const int c0 = (t & 127) * 4;   // col base
        float a0 = 0.f, a1 = 0.f, a2 = 0.f, a3 = 0.f;
        #pragma unroll
        for (int i = 0; i < 16; ++i) {
            int r = rg * 16 + i;
            float e = esh[r];
            uint32_t off = (uint32_t)(r * 1024 + c0 * 2) ^ (uint32_t)((r & 7) << 4);
            uint2 w = *(const uint2*)((const char*)xlds + off);
            a0 += e * bf2f(w.x & 0xffffu);
            a1 += e * bf2f(w.x >> 16);
            a2 += e * bf2f(w.y & 0xffffu);
            a3 += e * bf2f(w.y >> 16);
        }
        *(float4*)&plds[rg][c0] = make_float4(a0, a1, a2, a3);
    }
    __syncthreads();
    {
        float v = plds[0][t] + plds[1][t] + plds[2][t] + plds[3][t];
        vs[(size_t)wg * 512 + t] = v;
    }
}

// ---------------------------------------------------------------------------
// Kernel 2: per-bag combine. 32 blocks x 512 threads.
// ---------------------------------------------------------------------------
__global__ __launch_bounds__(512) void combine(
    const float* __restrict__ ms, const float* __restrict__ esums,
    const float* __restrict__ vs, const float* __restrict__ escore,
    float* __restrict__ A, float* __restrict__ pooled)
{
    const int bag = blockIdx.x;
    const int t   = threadIdx.x;
    __shared__ float alpha[64];

    if (t < 64) {
        float m = ms[bag * 64 + t];
        float M = m;
        #pragma unroll
        for (int o = 32; o; o >>= 1) M = fmaxf(M, __shfl_xor(M, o));
        float w = esums[bag * 64 + t] * __expf(m - M);
        float T = w;
        #pragma unroll
        for (int o = 32; o; o >>= 1) T += __shfl_xor(T, o);
        alpha[t] = __expf(m - M) / T;
    }
    __syncthreads();

    float acc = 0.f;
    #pragma unroll 8
    for (int c = 0; c < 64; ++c)
        acc += alpha[c] * vs[((size_t)bag * 64 + c) * 512 + t];
    pooled[(size_t)bag * 512 + t] = acc;

    #pragma unroll
    for (int i = 0; i < 8; ++i) {
        int n = i * 512 + t;
        A[(size_t)bag * Nz + n] = escore[(size_t)bag * Nz + n] * alpha[n >> 6];
    }
}

// ---------------------------------------------------------------------------
extern "C" void kernel_launch(void* const* d_in, const int* in_sizes, int n_in,
                              void* d_out, int out_size, void* d_ws, size_t ws_size,
                              hipStream_t stream)
{
    const float* x  = (const float*)d_in[0];
    const float* Wa = (const float*)d_in[1];
    const float* ba = (const float*)d_in[2];
    const float* Wb = (const float*)d_in[3];
    const float* bb = (const float*)d_in[4];
    const float* Wc = (const float*)d_in[5];
    const float* bc = (const float*)d_in[6];

    float* out    = (float*)d_out;
    float* A      = out;
    float* xcopy  = out + (size_t)Mz;
    float* pooled = xcopy + (size_t)Mz * Lz;

    char* ws = (char*)d_ws;
    unsigned short* packed = (unsigned short*)ws;                 // 512 KiB
    float* escore = (float*)(ws + 524288);                        // 512 KiB
    float* ms     = (float*)(ws + 1048576);                       // 8 KiB
    float* esums  = (float*)(ws + 1056768);                       // 8 KiB
    float* vs     = (float*)(ws + 1064960);                       // 4 MiB

    pack_w      <<<128, 256, 0, stream>>>(Wa, Wb, packed);
    fused_scores<<<Mz / 64, 512, 0, stream>>>(x, packed, ba, bb, Wc, bc,
                                              xcopy, escore, ms, esums, vs);
    combine     <<<Bz, 512, 0, stream>>>(ms, esums, vs, escore, A, pooled);
}